// Round 12
// baseline (270.484 us; speedup 1.0000x reference)
//
#include <hip/hip_runtime.h>
#include <hip/hip_bf16.h>
#include <hip/hip_cooperative_groups.h>

namespace cg = cooperative_groups;

#define NN   50000
#define NE   800000
#define F_IN 128
#define F_H  128
#define F_O  64

#define BINSHIFT 7                       // 128 nodes per bin
#define NBINS    ((NN + 127) >> 7)       // 391
#define CAP      2816                    // per-bin capacity (mean 2048, +17 sigma)
#define EPB      8192                    // edges per binning block
#define RSS      (NBINS + 1)             // rs row stride (392)
#define HS       132                     // Htile row stride in bf16 (2-way alias only)

static constexpr int NB_GEMM = (NN + 127) / 128;       // 391 GEMM blocks (128 rows, 8 waves)
static constexpr int NB_BIN  = (NE + EPB - 1) / EPB;   // 98 binning blocks

typedef __bf16 bf16_8 __attribute__((ext_vector_type(8)));
typedef float  f32x4  __attribute__((ext_vector_type(4)));

// ---------------------------------------------------------------------------
// MFMA GEMM body, 512 threads / 128 rows per block (8 waves x 16 rows) — the
// r11 form that broke fuseA's 44us occupancy floor. W staged once, swizzled
// to B-fragment layout [ks][c][q][r][j] (r-stride 16B: all 8 LDS bank-groups).
// mfma_f32_16x16x32_bf16: A[m=lane&15][k=(lane>>4)*8+j],
//                         B[k][n=lane&15], D[row=(lane>>4)*4+reg][col=lane&15].
// ---------------------------------------------------------------------------
template <typename AT, int K, int NOUT>
__device__ __forceinline__ void gemm_body512(const AT* __restrict__ X,
                                             const float* __restrict__ W,
                                             __hip_bfloat16* __restrict__ Y,
                                             __hip_bfloat16* WB, int blk) {
    constexpr int NKS = K / 32;
    constexpr int NC  = NOUT / 16;
    const int t = threadIdx.x;
    for (int f = t; f < K * NOUT; f += 512) {
        int k = f / NOUT, n = f % NOUT;
        int ks = k >> 5, kr = k & 31, qq = kr >> 3, jj = kr & 7;
        int c = n >> 4, nn = n & 15;
        WB[(((ks * NC + c) * 4 + qq) * 16 + nn) * 8 + jj] = __float2bfloat16(W[f]);
    }
    __syncthreads();

    const int wave = t >> 6, lane = t & 63;
    const int r = lane & 15, q = lane >> 4;
    const int m0 = blk * 128 + wave * 16;
    int arow = m0 + r;
    if (arow >= NN) arow = NN - 1;  // clamp: garbage rows computed, never stored

    f32x4 acc[NC];
#pragma unroll
    for (int c = 0; c < NC; ++c) acc[c] = (f32x4){0.f, 0.f, 0.f, 0.f};

#pragma unroll
    for (int ks = 0; ks < NKS; ++ks) {
        bf16_8 a;
        if constexpr (sizeof(AT) == 4) {
            const float* xp = (const float*)X + (size_t)arow * K + ks * 32 + q * 8;
            float4 x0 = ((const float4*)xp)[0];
            float4 x1 = ((const float4*)xp)[1];
            a[0] = (__bf16)x0.x; a[1] = (__bf16)x0.y; a[2] = (__bf16)x0.z; a[3] = (__bf16)x0.w;
            a[4] = (__bf16)x1.x; a[5] = (__bf16)x1.y; a[6] = (__bf16)x1.z; a[7] = (__bf16)x1.w;
        } else {
            a = *(const bf16_8*)((const __hip_bfloat16*)X + (size_t)arow * K + ks * 32 + q * 8);
        }
#pragma unroll
        for (int c = 0; c < NC; ++c) {
            bf16_8 b = *(const bf16_8*)&WB[(((ks * NC + c) * 4 + q) * 16 + r) * 8];
            acc[c] = __builtin_amdgcn_mfma_f32_16x16x32_bf16(a, b, acc[c], 0, 0, 0);
        }
    }

#pragma unroll
    for (int c = 0; c < NC; ++c) {
#pragma unroll
        for (int i = 0; i < 4; ++i) {
            int gr = m0 + q * 4 + i;
            if (gr < NN)
                Y[(size_t)gr * NOUT + c * 16 + r] = __float2bfloat16(acc[c][i]);
        }
    }
}

// ---------------------------------------------------------------------------
// Fused front: blocks [0, NB_BIN): bin-sort EPB edges into the block's OWN
// contiguous binbuf region via LDS hist + LDS scan + LDS-cursor scatter.
// Plain stores only — no global atomics, nothing pre-zeroed (memset dispatch
// deleted). Per-block bin offsets go to rs[blk][0..391], rs[blk][391]=total.
// blocks [NB_BIN, ...): GEMM1 (x@W1 -> Xw raw row-major).
// Packed entry: (src << 7) | (dst & 127).
// ---------------------------------------------------------------------------
__global__ __launch_bounds__(512) void k_fuseA(const float* __restrict__ X,
                                               const float* __restrict__ W1,
                                               __hip_bfloat16* __restrict__ Xw,
                                               const int* __restrict__ ei32,
                                               int* __restrict__ binbuf,
                                               unsigned* __restrict__ rs) {
    __shared__ __align__(16) char smem[32768];  // GEMM WB (32KB) / binning hist+scan
    const int t = threadIdx.x;

    if (blockIdx.x >= NB_BIN) {
        gemm_body512<float, F_IN, F_H>(X, W1, Xw, (__hip_bfloat16*)smem,
                                       blockIdx.x - NB_BIN);
        return;
    }

    unsigned* hist = (unsigned*)smem;        // [NBINS] -> becomes cursors
    unsigned* ofs  = hist + 512;             // [512] scan space
    for (int i = t; i < NBINS; i += 512) hist[i] = 0u;
    __syncthreads();

    const bool is64 = ((ei32[1] | ei32[3] | ei32[5] | ei32[7]) == 0);
    const long long* p64 = (const long long*)ei32;
    const int e0 = blockIdx.x * EPB;
    const int e1 = (e0 + EPB < NE) ? e0 + EPB : NE;

    for (int e = e0 + t; e < e1; e += 512) {
        int d = is64 ? (int)p64[NE + e] : ei32[NE + e];
        atomicAdd(&hist[d >> BINSHIFT], 1u);  // LDS
    }
    __syncthreads();

    unsigned v = (t < NBINS) ? hist[t] : 0u;
    ofs[t] = v;
    __syncthreads();
    for (int off = 1; off < 512; off <<= 1) {
        unsigned u = (t >= off) ? ofs[t - off] : 0u;
        __syncthreads();
        ofs[t] += u;
        __syncthreads();
    }
    if (t < NBINS) {
        unsigned ex = ofs[t] - v;            // exclusive
        rs[blockIdx.x * RSS + t] = ex;
        hist[t] = ex;                        // cursor
    }
    if (t == 0) rs[blockIdx.x * RSS + NBINS] = (unsigned)(e1 - e0);
    __syncthreads();

    for (int e = e0 + t; e < e1; e += 512) {
        int s, d;
        if (is64) { s = (int)p64[e]; d = (int)p64[NE + e]; }
        else      { s = ei32[e];     d = ei32[NE + e]; }
        unsigned pos = atomicAdd(&hist[d >> BINSHIFT], 1u);  // LDS
        binbuf[e0 + pos] = (s << BINSHIFT) | (d & 127);
    }
}

// ---------------------------------------------------------------------------
// Cooperative mega-kernel, one block (512 thr) per bin of 128 dst nodes:
//  P1: gather this bin's 98 chunks (offsets from rs) -> srcsL (LDS); 128-node
//      hist + scan -> dinv global + LDS cursors; scatter -> csrL (LDS CSR,
//      never round-trips global).
//  grid.sync()  [all dinv visible]
//  P2: agg1 (r7 form: 16 lanes x 16B, 4 slots, 2-deep, per-edge dinv[src]),
//      H1 rows -> LDS Htile only (12.8MB global round-trip deleted).
//  __syncthreads (block-local: gemm2 rows == this block's agg1 rows)
//  P3: gemm2 on LDS Htile (stage W2 swizzled) -> Hw global, scaled by dinv[v].
//  grid.sync()  [all Hw visible]
//  P4: agg2 (8 lanes x 16B, 2-deep) from csrL -> out (f32).
// ---------------------------------------------------------------------------
__global__ __launch_bounds__(512) void k_mega(const int* __restrict__ binbuf,
                                              const unsigned* __restrict__ rs,
                                              const __hip_bfloat16* __restrict__ Xw,
                                              const float* __restrict__ W2,
                                              const float* __restrict__ b1,
                                              const float* __restrict__ b2,
                                              float* __restrict__ dinvG,
                                              __hip_bfloat16* __restrict__ Hw,
                                              float* __restrict__ out) {
    cg::grid_group grid = cg::this_grid();

    __shared__ __align__(16) char smem[64512];
    __hip_bfloat16* Htile = (__hip_bfloat16*)smem;            // 128*HS*2 = 33792 (P2+)
    int*      srcsL = (int*)smem;                             // CAP*4 = 11264 (P1, aliases Htile)
    int*      csrL  = (int*)(smem + 33792);                   // CAP*4 = 11264
    __hip_bfloat16* W2B = (__hip_bfloat16*)(smem + 45056);    // 16384
    unsigned* stL  = (unsigned*)(smem + 61440);               // 128*4
    unsigned* lenL = (unsigned*)(smem + 61952);               // 128*4
    unsigned* lofs = (unsigned*)(smem + 62464);               // 128*4
    unsigned* h    = (unsigned*)(smem + 62976);               // 128*4
    unsigned* cur  = (unsigned*)(smem + 63488);               // 128*4
    float*    dv   = (float*)(smem + 64000);                  // 128*4

    const int bb = blockIdx.x, t = threadIdx.x;
    const int wave = t >> 6, lane = t & 63;

    // ---- P1: chunk table + inclusive scan of lens ----
    if (t < 128) {
        unsigned s0 = 0, ln = 0;
        if (t < NB_BIN) {
            s0 = rs[t * RSS + bb];
            ln = rs[t * RSS + bb + 1] - s0;
        }
        stL[t] = s0;
        lenL[t] = ln;
        lofs[t] = ln;
        h[t] = 0u;
    }
    __syncthreads();
    for (int off = 1; off < 128; off <<= 1) {
        unsigned u = (t < 128 && t >= off) ? lofs[t - off] : 0u;
        __syncthreads();
        if (t < 128) lofs[t] += u;
        __syncthreads();
    }
    const unsigned n = lofs[NB_BIN - 1];   // bin's total edges

    // gather chunks -> srcsL
    for (unsigned i = t; i < n; i += 512) {
        int lo = 0, hi = NB_BIN - 1;
        while (lo < hi) {                   // first c with lofs[c] > i
            int mid = (lo + hi) >> 1;
            if (lofs[mid] > i) hi = mid; else lo = mid + 1;
        }
        unsigned within = i - (lofs[lo] - lenL[lo]);
        srcsL[i] = binbuf[lo * EPB + stL[lo] + within];
    }
    __syncthreads();

    // 128-node histogram + scan
    for (unsigned i = t; i < n; i += 512)
        atomicAdd(&h[srcsL[i] & 127], 1u);
    __syncthreads();
    if (t < 128) cur[t] = h[t];
    __syncthreads();
    for (int off = 1; off < 128; off <<= 1) {
        unsigned u = (t < 128 && t >= off) ? cur[t - off] : 0u;
        __syncthreads();
        if (t < 128) cur[t] += u;
        __syncthreads();
    }
    if (t < 128) {
        unsigned ex = cur[t] - h[t];
        int node = (bb << BINSHIFT) + t;
        float d = rsqrtf((float)(h[t] + 1u));  // +1 self-loop
        dv[t] = d;
        if (node < NN) dinvG[node] = d;
        cur[t] = ex;                            // scatter cursor
    }
    __syncthreads();
    for (unsigned i = t; i < n; i += 512) {
        int p = srcsL[i];
        unsigned pos = atomicAdd(&cur[p & 127], 1u);
        csrL[pos] = p >> BINSHIFT;
    }
    // after scatter: cur[tl] = end, cur[tl]-h[tl] = start

    grid.sync();   // all bins' dinvG written; srcsL dead -> Htile may reuse

    // ---- P2: agg1, 16 nodes per wave ----
    {
        const int sub = lane >> 4, fl = lane & 15;
        float b1r[8];
        {
            float4 ba = ((const float4*)b1)[fl * 2];
            float4 bbv = ((const float4*)b1)[fl * 2 + 1];
            b1r[0] = ba.x; b1r[1] = ba.y; b1r[2] = ba.z; b1r[3] = ba.w;
            b1r[4] = bbv.x; b1r[5] = bbv.y; b1r[6] = bbv.z; b1r[7] = bbv.w;
        }
        for (int k = 0; k < 16; ++k) {
            const int tl = k * 8 + wave;
            const int gnode = (bb << BINSHIFT) + tl;
            const unsigned i1 = cur[tl];
            const unsigned i0 = i1 - h[tl];
            const float dn = dv[tl];
            int srow = (gnode < NN) ? gnode : 0;
            bf16_8 self = *(const bf16_8*)(Xw + (size_t)srow * F_H + fl * 8);
            float acc0[8], acc1[8];
#pragma unroll
            for (int j = 0; j < 8; ++j) {
                acc0[j] = (sub == 0 && gnode < NN) ? dn * (float)self[j] : 0.f;
                acc1[j] = 0.f;
            }
            unsigned i = i0 + sub;
            for (; i + 4 < i1; i += 8) {
                int s0 = csrL[i], s1 = csrL[i + 4];
                float d0 = dinvG[s0], d1 = dinvG[s1];
                bf16_8 r0 = *(const bf16_8*)(Xw + (size_t)s0 * F_H + fl * 8);
                bf16_8 r1 = *(const bf16_8*)(Xw + (size_t)s1 * F_H + fl * 8);
#pragma unroll
                for (int j = 0; j < 8; ++j) {
                    acc0[j] += d0 * (float)r0[j];
                    acc1[j] += d1 * (float)r1[j];
                }
            }
            if (i < i1) {
                int s = csrL[i];
                float d = dinvG[s];
                bf16_8 r = *(const bf16_8*)(Xw + (size_t)s * F_H + fl * 8);
#pragma unroll
                for (int j = 0; j < 8; ++j) acc0[j] += d * (float)r[j];
            }
#pragma unroll
            for (int j = 0; j < 8; ++j) {
                float a = acc0[j] + acc1[j];
                a += __shfl_xor(a, 16, 64);
                a += __shfl_xor(a, 32, 64);
                acc0[j] = a;
            }
            if (sub == 0) {
                bf16_8 o;
#pragma unroll
                for (int j = 0; j < 8; ++j) {
                    float vv = fmaxf(dn * acc0[j] + b1r[j], 0.f);
                    o[j] = (gnode < NN) ? (__bf16)vv : (__bf16)0.f;
                }
                *(bf16_8*)(Htile + tl * HS + fl * 8) = o;
            }
        }
    }

    // stage W2 swizzled (region untouched so far)
    for (int f = t; f < F_H * F_O; f += 512) {
        int k = f >> 6, nc = f & 63;
        int ks = k >> 5, kr = k & 31, qq = kr >> 3, jj = kr & 7;
        int c = nc >> 4, nn = nc & 15;
        W2B[(((ks * 4 + c) * 4 + qq) * 16 + nn) * 8 + jj] = __float2bfloat16(W2[f]);
    }
    __syncthreads();   // Htile + W2B ready (block-local dependency only)

    // ---- P3: gemm2 on LDS Htile -> Hw (scaled by dinv[v]) ----
    {
        const int r = lane & 15, q = lane >> 4;
        const int rt = wave;                  // 16 rows per wave
        f32x4 acc[4];
#pragma unroll
        for (int c = 0; c < 4; ++c) acc[c] = (f32x4){0.f, 0.f, 0.f, 0.f};
#pragma unroll
        for (int ks = 0; ks < 4; ++ks) {
            bf16_8 a = *(const bf16_8*)(Htile + (rt * 16 + r) * HS + ks * 32 + q * 8);
#pragma unroll
            for (int c = 0; c < 4; ++c) {
                bf16_8 bfr = *(const bf16_8*)&W2B[(((ks * 4 + c) * 4 + q) * 16 + r) * 8];
                acc[c] = __builtin_amdgcn_mfma_f32_16x16x32_bf16(a, bfr, acc[c], 0, 0, 0);
            }
        }
#pragma unroll
        for (int c = 0; c < 4; ++c) {
#pragma unroll
            for (int i = 0; i < 4; ++i) {
                int tl = rt * 16 + q * 4 + i;
                int gnode = (bb << BINSHIFT) + tl;
                if (gnode < NN)
                    Hw[(size_t)gnode * F_O + c * 16 + r] =
                        __float2bfloat16(dv[tl] * acc[c][i]);
            }
        }
    }

    grid.sync();   // all Hw visible

    // ---- P4: agg2, 16 nodes per wave ----
    {
        const int sub = lane >> 3, fl = lane & 7;
        float b2r[8];
        {
            float4 ba = ((const float4*)b2)[fl * 2];
            float4 bbv = ((const float4*)b2)[fl * 2 + 1];
            b2r[0] = ba.x; b2r[1] = ba.y; b2r[2] = ba.z; b2r[3] = ba.w;
            b2r[4] = bbv.x; b2r[5] = bbv.y; b2r[6] = bbv.z; b2r[7] = bbv.w;
        }
        for (int k = 0; k < 16; ++k) {
            const int tl = k * 8 + wave;
            const int gnode = (bb << BINSHIFT) + tl;
            if (gnode >= NN) continue;
            const unsigned i1 = cur[tl];
            const unsigned i0 = i1 - h[tl];
            bf16_8 self = *(const bf16_8*)(Hw + (size_t)gnode * F_O + fl * 8);
            float acc0[8], acc1[8];
#pragma unroll
            for (int j = 0; j < 8; ++j) {
                acc0[j] = (sub == 0) ? (float)self[j] : 0.f;
                acc1[j] = 0.f;
            }
            unsigned i = i0 + sub;
            for (; i + 8 < i1; i += 16) {
                int s0 = csrL[i], s1 = csrL[i + 8];
                bf16_8 r0 = *(const bf16_8*)(Hw + (size_t)s0 * F_O + fl * 8);
                bf16_8 r1 = *(const bf16_8*)(Hw + (size_t)s1 * F_O + fl * 8);
#pragma unroll
                for (int j = 0; j < 8; ++j) {
                    acc0[j] += (float)r0[j];
                    acc1[j] += (float)r1[j];
                }
            }
            if (i < i1) {
                bf16_8 r = *(const bf16_8*)(Hw + (size_t)csrL[i] * F_O + fl * 8);
#pragma unroll
                for (int j = 0; j < 8; ++j) acc0[j] += (float)r[j];
            }
#pragma unroll
            for (int j = 0; j < 8; ++j) {
                float a = acc0[j] + acc1[j];
                a += __shfl_xor(a, 8, 64);
                a += __shfl_xor(a, 16, 64);
                a += __shfl_xor(a, 32, 64);
                acc0[j] = a;
            }
            if (sub == 0) {
                float dn = dv[tl];
                float4 o0 = make_float4(dn * acc0[0] + b2r[0], dn * acc0[1] + b2r[1],
                                        dn * acc0[2] + b2r[2], dn * acc0[3] + b2r[3]);
                float4 o1 = make_float4(dn * acc0[4] + b2r[4], dn * acc0[5] + b2r[5],
                                        dn * acc0[6] + b2r[6], dn * acc0[7] + b2r[7]);
                float4* op = (float4*)(out + (size_t)gnode * F_O + fl * 8);
                op[0] = o0;
                op[1] = o1;
            }
        }
    }
}

// ---------------------------------------------------------------------------
extern "C" void kernel_launch(void* const* d_in, const int* in_sizes, int n_in,
                              void* d_out, int out_size, void* d_ws, size_t ws_size,
                              hipStream_t stream) {
    const float* x  = (const float*)d_in[0];
    const int*   ei = (const int*)d_in[1];
    const float* W1 = (const float*)d_in[2];
    const float* b1 = (const float*)d_in[3];
    const float* W2 = (const float*)d_in[4];
    const float* b2 = (const float*)d_in[5];
    float* out = (float*)d_out;

    char* w = (char*)d_ws;
    size_t off = 0;
    auto alloc = [&](size_t bytes) {
        void* p = w + off;
        off += (bytes + 255) & ~(size_t)255;
        return p;
    };
    int*      binbuf = (int*)alloc((size_t)NB_BIN * EPB * 4);
    unsigned* rs     = (unsigned*)alloc((size_t)NB_BIN * RSS * 4);
    float*    dinv   = (float*)alloc((size_t)NN * 4);
    __hip_bfloat16* Xw = (__hip_bfloat16*)alloc((size_t)NN * F_H * 2);
    __hip_bfloat16* Hw = (__hip_bfloat16*)alloc((size_t)NN * F_O * 2);  // NOT aliased with Xw
                                                                        // (P2 reads Xw while other
                                                                        // blocks' P3 writes Hw)

    k_fuseA<<<NB_BIN + NB_GEMM, 512, 0, stream>>>(x, W1, Xw, ei, binbuf, rs);

    void* kargs[] = {(void*)&binbuf, (void*)&rs, (void*)&Xw, (void*)&W2,
                     (void*)&b1, (void*)&b2, (void*)&dinv, (void*)&Hw, (void*)&out};
    hipLaunchCooperativeKernel((void*)k_mega, dim3(NBINS), dim3(512), kargs, 0, stream);
}